// Round 1
// baseline (177.604 us; speedup 1.0000x reference)
//
#include <hip/hip_runtime.h>
#include <math.h>

// ODE2: swing-equation Euler integration, one thread per batch element.
// B=16384 -> 256 waves total: latency-bound on the sequential substep chain.
// block=64, grid=256: one wave per CU across all 256 CUs (max SIMD coverage).

#define NSUB 10
#define STEP 1e-4f
#define PQ_SCALE 22.2f

__global__ __launch_bounds__(64) void ode2_kernel(
    const float* __restrict__ x,      // (B, T, 2) : vt, phi
    const float* __restrict__ y0,     // (B, 3)    : delta, omega, e1q
    const float* __restrict__ s,      // (9,)
    const float* __restrict__ th,     // (9,)
    float* __restrict__ out,          // (B, T, 2) : p, q
    int B, int T)
{
    int b = blockIdx.x * 64 + threadIdx.x;
    if (b >= B) return;

    // Wave-uniform constants (scalar loads + scalar math expected).
    float a  = s[0] * th[0];
    float bb = s[1] * th[1];
    float k2 = s[2] * th[2];
    float c  = s[3] * th[3];
    float M  = s[4] * th[4];
    float k5 = s[5] * th[5];
    float k6 = s[6] * th[6];
    float k7 = s[7] * th[7];
    float Te = s[8] * th[8];
    float invD = 1.0f / (bb * c + a * a);
    float invM = 1.0f / M;
    float invT = 1.0f / Te;
    float aD = a * invD, bD = bb * invD, cD = c * invD;

    float delta = y0[b * 3 + 0];
    float omega = y0[b * 3 + 1];
    float e1q   = y0[b * 3 + 2];

    const float2* xb = (const float2*)x + (size_t)b * T;
    float2*       ob = (float2*)out     + (size_t)b * T;

    float2 u = xb[0];
    for (int t = 0; t < T; ++t) {
        // Prefetch next interval's exogenous input early so the global load
        // overlaps the ~450-cycle substep chain below.
        int tn = t + 1 < T ? t + 1 : t;
        float2 u_next = xb[tn];

        float vt = u.x, phi = u.y;
        float sn, cs;
        __sincosf(delta - phi, &sn, &cs);

        // Output at time t (state = preds[t], u = y_exog[t]).
        float vd = vt * sn, vq = vt * cs;
        float E  = e1q - vq;
        float id = cD * E - aD * vd;
        float iq = aD * E + bD * vd;
        float pe = vd * id + vq * iq;
        float qq = vq * id - vd * iq;
        ob[t] = make_float2(PQ_SCALE * pe, PQ_SCALE * qq);

        if (t == T - 1) break;

        // Substep 0 of interval t reuses the sincos/currents above.
        float d_omega = (k6 - pe - k5 * omega) * invM;
        float d_e1q   = (k7 - e1q - k2 * id) * invT;
        delta += STEP * omega;      // uses old omega (Euler)
        omega += STEP * d_omega;
        e1q   += STEP * d_e1q;

        #pragma unroll
        for (int kk = 1; kk < NSUB; ++kk) {
            __sincosf(delta - phi, &sn, &cs);
            vd = vt * sn; vq = vt * cs;
            E  = e1q - vq;
            id = cD * E - aD * vd;
            iq = aD * E + bD * vd;
            pe = vd * id + vq * iq;
            d_omega = (k6 - pe - k5 * omega) * invM;
            d_e1q   = (k7 - e1q - k2 * id) * invT;
            delta += STEP * omega;
            omega += STEP * d_omega;
            e1q   += STEP * d_e1q;
        }

        u = u_next;
    }
}

extern "C" void kernel_launch(void* const* d_in, const int* in_sizes, int n_in,
                              void* d_out, int out_size, void* d_ws, size_t ws_size,
                              hipStream_t stream) {
    const float* x     = (const float*)d_in[0];
    const float* y0    = (const float*)d_in[1];
    // d_in[2] = t (unused by the reference computation)
    const float* s     = (const float*)d_in[3];
    const float* theta = (const float*)d_in[4];
    float* out = (float*)d_out;

    int B = in_sizes[1] / 3;   // 16384
    int T = in_sizes[2];       // 200

    int block = 64;
    int grid = (B + block - 1) / block;  // 256 blocks -> 1 wave per CU
    ode2_kernel<<<grid, block, 0, stream>>>(x, y0, s, theta, out, B, T);
}

// Round 2
// 148.585 us; speedup vs baseline: 1.1953x; 1.1953x over previous
//
#include <hip/hip_runtime.h>
#include <math.h>

// ODE2: swing-equation Euler integration, one thread per batch element.
// B=16384 -> 256 waves = 1 wave/CU: latency-bound on the sequential substep
// chain. R1 measured 139 cyc/substep dominated by per-substep __sincosf.
// R2: replace per-substep sincos with first-order incremental rotation
// (eps = STEP*omega <= ~5e-5 -> rotation truncation ~1e-13/step) and flatten
// the Euler updates into affine recurrences with per-interval constants.
// Exact sincos only once per interval (phi changes there).

#define NSUB 10
#define STEP 1e-4f
#define PQ_SCALE 22.2f

__global__ __launch_bounds__(64) void ode2_kernel(
    const float* __restrict__ x,      // (B, T, 2) : vt, phi
    const float* __restrict__ y0,     // (B, 3)    : delta, omega, e1q
    const float* __restrict__ s,      // (9,)
    const float* __restrict__ th,     // (9,)
    float* __restrict__ out,          // (B, T, 2) : p, q
    int B, int T)
{
    int b = blockIdx.x * 64 + threadIdx.x;
    if (b >= B) return;

    // Wave-uniform constants.
    float a  = s[0] * th[0];
    float bb = s[1] * th[1];
    float k2 = s[2] * th[2];
    float c  = s[3] * th[3];
    float M  = s[4] * th[4];
    float k5 = s[5] * th[5];
    float k6 = s[6] * th[6];
    float k7 = s[7] * th[7];
    float Te = s[8] * th[8];
    float invD = 1.0f / (bb * c + a * a);
    float invM = 1.0f / M;
    float invT = 1.0f / Te;
    float aD = a * invD, bD = bb * invD, cD = c * invD;

    const float h = STEP;
    // e1q' = alpha*e1q + (bk7 + W*(cD*cs + aD*sn)),  W = h*invT*k2*vt (per-interval)
    float alpha = 1.0f - h * invT * (1.0f + k2 * cD);
    float bk7   = h * invT * k7;
    float wcoef = h * invT * k2;
    // omega' = gamma*omega + (mu - nu*pe)
    float gamma = 1.0f - h * invM * k5;
    float mu    = h * invM * k6;
    float nu    = h * invM;

    float delta = y0[b * 3 + 0];
    float omega = y0[b * 3 + 1];
    float e1q   = y0[b * 3 + 2];

    const float2* xb = (const float2*)x + (size_t)b * T;
    float2*       ob = (float2*)out     + (size_t)b * T;

    float2 u = xb[0];
    for (int t = 0; t < T; ++t) {
        int tn = t + 1 < T ? t + 1 : t;
        float2 u_next = xb[tn];   // prefetch hides under the chain below

        float vt = u.x, phi = u.y;
        float sn, cs;
        __sincosf(delta - phi, &sn, &cs);

        // Output at time t (direct formula; once per interval, off hot chain).
        float vd = vt * sn, vq = vt * cs;
        float E  = e1q - vq;
        float id = cD * E - aD * vd;
        float iq = aD * E + bD * vd;
        float p  = vd * id + vq * iq;
        float q  = vq * id - vd * iq;
        ob[t] = make_float2(PQ_SCALE * p, PQ_SCALE * q);

        if (t == T - 1) break;

        // Per-interval constants.
        float Pc = vt * cD;               // pe combo: Pc*sn + Qa*cs
        float Qa = vt * aD;
        float R  = (bD - cD) * vt * vt;   // pe = e1q*t1 + R*sn*cs - S
        float S  = aD * vt * vt;
        float Wc = wcoef * vt * cD;       // e1q combo
        float Wa = wcoef * vt * aD;

        #pragma unroll
        for (int kk = 0; kk < NSUB; ++kk) {
            // All RHS terms from OLD (sn, cs, e1q, omega).
            float t1  = fmaf(Pc, sn, Qa * cs);               // vt*(cD*sn + aD*cs)
            float t2  = sn * cs;
            float pe  = fmaf(e1q, t1, fmaf(R, t2, -S));
            float eacc = fmaf(Wc, cs, fmaf(Wa, sn, bk7));
            float eps = h * omega;                           // uses old omega
            float n_omega = fmaf(gamma, omega, fmaf(-nu, pe, mu));
            float n_e1q   = fmaf(alpha, e1q, eacc);
            delta = fmaf(h, omega, delta);
            float n_sn = fmaf(eps, cs, sn);                  // first-order rotation
            float n_cs = fmaf(-eps, sn, cs);
            omega = n_omega; e1q = n_e1q; sn = n_sn; cs = n_cs;
        }

        u = u_next;
    }
}

extern "C" void kernel_launch(void* const* d_in, const int* in_sizes, int n_in,
                              void* d_out, int out_size, void* d_ws, size_t ws_size,
                              hipStream_t stream) {
    const float* x     = (const float*)d_in[0];
    const float* y0    = (const float*)d_in[1];
    // d_in[2] = t (unused by the reference computation)
    const float* s     = (const float*)d_in[3];
    const float* theta = (const float*)d_in[4];
    float* out = (float*)d_out;

    int B = in_sizes[1] / 3;   // 16384
    int T = in_sizes[2];       // 200

    int block = 64;
    int grid = (B + block - 1) / block;  // 256 blocks -> 1 wave per CU
    ode2_kernel<<<grid, block, 0, stream>>>(x, y0, s, theta, out, B, T);
}